// Round 1
// baseline (311.527 us; speedup 1.0000x reference)
//
#include <hip/hip_runtime.h>

// GateSparsemaxK: per-row (R=4096) gated sparsemax, scaled by k, clipped to [0,1].
// z = where(mask>0.5, s, -1e9)/0.7 ; p = sparsemax(z) ; out = min(k*p, 1)
//
// R5 theory: R1-R4 plateaued far below the 402MB/6.3TB/s ~= 64us streaming
// floor because the row unit was a 4-wave BLOCK: every Michelot iteration
// crossed an LDS+__syncthreads reduction, and the 4 resident blocks/CU
// advanced in lockstep phases -> long windows with no loads in flight.
// This version makes the row unit a WAVE:
//   - 64 elements/lane (16 float4), z lives entirely in registers (64 VGPRs)
//   - mask staged in two 8-chunk halves (32 VGPRs) to stay under the 128-VGPR
//     / 16-waves-per-CU occupancy boundary
//   - ZERO __syncthreads, ZERO LDS: Michelot reduces via __shfl_xor only
//   - support count via __ballot + __popcll -> scalar pipe (s_bcnt1), sharing
//     the v_cmp with the conditional sum; only ssum rides the butterfly
//   - 4 independent rows per 256-thread block; 16 resident waves/CU
//     desynchronize so load phases of some rows overlap iterate phases of
//     others -> memory pipe stays fed.

#define R_DIM 4096
#define BLOCK 256
#define RPB   4                  // rows per block = waves per block
#define NCH   16                 // float4 chunks per lane: 4096 / (4*64)
#define BIG_NEG -1.0e9f
#define INV_TAU (1.0f / 0.7f)

typedef float fx4 __attribute__((ext_vector_type(4)));   // builtin-compatible float4

__device__ __forceinline__ void gate4(fx4& zv, const fx4 mv, float& zmax)
{
    zv.x = (mv.x > 0.5f ? zv.x : BIG_NEG) * INV_TAU;
    zv.y = (mv.y > 0.5f ? zv.y : BIG_NEG) * INV_TAU;
    zv.z = (mv.z > 0.5f ? zv.z : BIG_NEG) * INV_TAU;
    zv.w = (mv.w > 0.5f ? zv.w : BIG_NEG) * INV_TAU;
    zmax = fmaxf(zmax, fmaxf(fmaxf(zv.x, zv.y), fmaxf(zv.z, zv.w)));
}

__global__ __launch_bounds__(BLOCK, 4)   // 4 blocks/CU * 4 waves = 16 waves/CU, VGPR<=128
void gate_sparsemax_k_kernel(const float* __restrict__ s,
                             const float* __restrict__ m,
                             const int*  __restrict__ kptr,
                             float* __restrict__ out,
                             int nrows)
{
    const int tid  = (int)threadIdx.x;
    const int lane = tid & 63;
    const int wid  = tid >> 6;
    const int row  = (int)blockIdx.x * RPB + wid;   // wave-uniform
    if (row >= nrows) return;                       // whole wave exits together

    const float kf = (float)(*kptr);

    const size_t base = (size_t)row * R_DIM;
    const fx4* sv4 = (const fx4*)(s + base);
    const fx4* mv4 = (const fx4*)(m + base);
    fx4*       ov4 = (fx4*)(out + base);

    // ---- stage: issue all 16 s-loads + first 8 m-loads before any use ----
    fx4 zz[NCH];        // holds s, gated in place to z (64 VGPRs)
    fx4 mm[NCH / 2];    // half of mask at a time (32 VGPRs)

    #pragma unroll
    for (int t = 0; t < NCH; ++t)
        zz[t] = __builtin_nontemporal_load(&sv4[t * 64 + lane]);
    #pragma unroll
    for (int t = 0; t < NCH / 2; ++t)
        mm[t] = __builtin_nontemporal_load(&mv4[t * 64 + lane]);
    __builtin_amdgcn_sched_barrier(0);   // loads must not sink into their uses

    // ---- gate + scale first half; thread-local max ----
    float zmax = -3.4028235e38f;
    #pragma unroll
    for (int t = 0; t < NCH / 2; ++t)
        gate4(zz[t], mm[t], zmax);

    // ---- second half of mask (reuses mm regs), then gate ----
    #pragma unroll
    for (int t = 0; t < NCH / 2; ++t)
        mm[t] = __builtin_nontemporal_load(&mv4[(NCH / 2 + t) * 64 + lane]);
    __builtin_amdgcn_sched_barrier(0);
    #pragma unroll
    for (int t = 0; t < NCH / 2; ++t)
        gate4(zz[NCH / 2 + t], mm[t], zmax);

    // ---- wave-wide max: pure shfl butterfly (no LDS, no barrier) ----
    #pragma unroll
    for (int off = 32; off >= 1; off >>= 1)
        zmax = fmaxf(zmax, __shfl_xor(zmax, off, 64));

    // ---- Michelot iterations (exact sparsemax threshold, no sort) ----
    // tau0 = max-1 <= tau*; tau <- (sum_{z>tau} z - 1)/#{z>tau}. Support
    // shrinks monotonically; terminates exactly at the fixed point. All
    // lanes compute identical S (butterfly) and C (ballot popcount, scalar
    // pipe) -> wave-uniform break.
    float tau = zmax - 1.0f;
    for (int it = 0; it < 50; ++it) {
        float ssum = 0.0f;
        int cnt = 0;   // wave-total count, uniform (ballot spans all 64 lanes)
        #pragma unroll
        for (int t = 0; t < NCH; ++t) {
            const fx4 zv = zz[t];
            ssum += (zv.x > tau) ? zv.x : 0.0f;
            cnt  += (int)__popcll(__ballot(zv.x > tau));
            ssum += (zv.y > tau) ? zv.y : 0.0f;
            cnt  += (int)__popcll(__ballot(zv.y > tau));
            ssum += (zv.z > tau) ? zv.z : 0.0f;
            cnt  += (int)__popcll(__ballot(zv.z > tau));
            ssum += (zv.w > tau) ? zv.w : 0.0f;
            cnt  += (int)__popcll(__ballot(zv.w > tau));
        }
        #pragma unroll
        for (int off = 32; off >= 1; off >>= 1)
            ssum += __shfl_xor(ssum, off, 64);

        const float C    = (float)cnt;           // >= 1: the max is in support
        const float tnew = (ssum - 1.0f) / C;
        if (tnew == tau) break;                  // exact fixed point, uniform
        tau = tnew;
    }

    // ---- epilogue: out = min(k * max(z - tau, 0), 1), nontemporal ----
    #pragma unroll
    for (int t = 0; t < NCH; ++t) {
        const fx4 zv = zz[t];
        fx4 ov;
        ov.x = fminf(kf * fmaxf(zv.x - tau, 0.0f), 1.0f);
        ov.y = fminf(kf * fmaxf(zv.y - tau, 0.0f), 1.0f);
        ov.z = fminf(kf * fmaxf(zv.z - tau, 0.0f), 1.0f);
        ov.w = fminf(kf * fmaxf(zv.w - tau, 0.0f), 1.0f);
        __builtin_nontemporal_store(ov, &ov4[t * 64 + lane]);
    }
}

extern "C" void kernel_launch(void* const* d_in, const int* in_sizes, int n_in,
                              void* d_out, int out_size, void* d_ws, size_t ws_size,
                              hipStream_t stream) {
    const float* s = (const float*)d_in[0];
    const float* m = (const float*)d_in[1];
    const int*   k = (const int*)d_in[2];
    float* out = (float*)d_out;

    const int nrows  = in_sizes[0] / R_DIM;            // 8192 rows
    const int nblk   = (nrows + RPB - 1) / RPB;        // 2048 blocks, 4 rows each
    gate_sparsemax_k_kernel<<<nblk, BLOCK, 0, stream>>>(s, m, k, out, nrows);
}

// Round 2
// 295.026 us; speedup vs baseline: 1.0559x; 1.0559x over previous
//
#include <hip/hip_runtime.h>

// GateSparsemaxK: per-row (R=4096) gated sparsemax, scaled by k, clipped to [0,1].
// z = where(mask>0.5, s, -1e9)/0.7 ; p = sparsemax(z) ; out = min(k*p, 1)
//
// R6 theory: R5 (wave-per-row) regressed: 64-elem dependent add chain per
// Michelot iter + register pressure (VGPR=64 < live set) beat the saved
// barriers. Revert to the proven block-per-row memory structure (~70us) and
// attack the iterate phase algebraically instead:
//   tau* >= zmax-1 and Michelot climbs monotonically from tau0 = zmax-1,
//   so every iteration's active set is a subset of C = {z > zmax-1}.
//   For gaussian rows |C| ~ 1-6. Compact C into LDS once (atomicAdd; nearly
//   no contention), then ALL threads run Michelot redundantly over <=n
//   broadcast LDS reads: ZERO barriers / shuffles / full-row scans per
//   iteration. Exact-equivalent to the full-scan loop; falls back to it if
//   |C| > CAP (e.g. fully-masked row -> all-equal z).
// Barriers per row: 2 (was ~8). Iterate cost per row: ~150 cyc (was ~3000).

#define R_DIM 4096
#define BLOCK 256
#define V4T   4                 // float4s per thread: 4096 / 4 / 256
#define CAP   128               // candidate buffer size (typ. |C| <= 8)
#define BIG_NEG -1.0e9f
#define INV_TAU (1.0f / 0.7f)

typedef float fx4 __attribute__((ext_vector_type(4)));   // builtin-compatible float4

__global__ __launch_bounds__(BLOCK, 6)   // cap VGPR<=85; actual ~50-60 -> 8 waves/EU
void gate_sparsemax_k_kernel(const float* __restrict__ s,
                             const float* __restrict__ m,
                             const int*  __restrict__ kptr,
                             float* __restrict__ out)
{
    __shared__ float red_max[4];
    __shared__ float cand[CAP];
    __shared__ int   ccnt;
    __shared__ float red_sum[2][4];   // fallback-path ping-pong slots
    __shared__ float red_cnt[2][4];

    const int tid  = (int)threadIdx.x;
    const int lane = tid & 63;
    const int wid  = tid >> 6;
    const int row  = (int)blockIdx.x;

    const float kf = (float)(*kptr);

    const size_t base = (size_t)row * R_DIM;
    const fx4* sv4 = (const fx4*)(s + base);
    const fx4* mv4 = (const fx4*)(m + base);
    fx4*       ov4 = (fx4*)(out + base);

    if (tid == 0) ccnt = 0;          // covered by the max-reduce barrier below

    // ---- issue ALL 8 global loads before any use --------------------------
    fx4 sv[V4T], mv[V4T];
    #pragma unroll
    for (int t = 0; t < V4T; ++t) sv[t] = __builtin_nontemporal_load(&sv4[t * BLOCK + tid]);
    #pragma unroll
    for (int t = 0; t < V4T; ++t) mv[t] = __builtin_nontemporal_load(&mv4[t * BLOCK + tid]);
    __builtin_amdgcn_sched_barrier(0);   // loads stay grouped above their uses

    // ---- gate + scale in registers; thread-local max ----------------------
    fx4 zz[V4T];
    float zmax = -3.4028235e38f;
    #pragma unroll
    for (int t = 0; t < V4T; ++t) {
        fx4 zv;
        zv.x = (mv[t].x > 0.5f ? sv[t].x : BIG_NEG) * INV_TAU;
        zv.y = (mv[t].y > 0.5f ? sv[t].y : BIG_NEG) * INV_TAU;
        zv.z = (mv[t].z > 0.5f ? sv[t].z : BIG_NEG) * INV_TAU;
        zv.w = (mv[t].w > 0.5f ? sv[t].w : BIG_NEG) * INV_TAU;
        zz[t] = zv;
        zmax = fmaxf(zmax, fmaxf(fmaxf(zv.x, zv.y), fmaxf(zv.z, zv.w)));
    }

    // ---- block-wide max: wave butterfly -> 4 LDS words -> combine ---------
    #pragma unroll
    for (int off = 32; off >= 1; off >>= 1)
        zmax = fmaxf(zmax, __shfl_xor(zmax, off, 64));
    if (lane == 0) red_max[wid] = zmax;
    __syncthreads();
    zmax = fmaxf(fmaxf(red_max[0], red_max[1]), fmaxf(red_max[2], red_max[3]));

    // ---- compact candidates {z > zmax-1} into LDS (exact superset of -----
    //      every Michelot active set, since tau_t climbs from zmax-1) ------
    const float thr = zmax - 1.0f;
    #pragma unroll
    for (int t = 0; t < V4T; ++t) {
        const fx4 zv = zz[t];
        if (zv.x > thr) { int i = atomicAdd(&ccnt, 1); if (i < CAP) cand[i] = zv.x; }
        if (zv.y > thr) { int i = atomicAdd(&ccnt, 1); if (i < CAP) cand[i] = zv.y; }
        if (zv.z > thr) { int i = atomicAdd(&ccnt, 1); if (i < CAP) cand[i] = zv.z; }
        if (zv.w > thr) { int i = atomicAdd(&ccnt, 1); if (i < CAP) cand[i] = zv.w; }
    }
    __syncthreads();
    const int ncand = ccnt;

    float tau = thr;
    if (ncand <= CAP) {
        // ---- Michelot over candidates: every thread redundantly, broadcast
        //      LDS reads (same addr all lanes -> no conflict), no barriers --
        for (int it = 0; it < 50; ++it) {
            float S = 0.0f; int C = 0;
            for (int i = 0; i < ncand; ++i) {
                const float c = cand[i];
                if (c > tau) { S += c; ++C; }
            }
            const float tnew = (S - 1.0f) / (float)C;   // C>=1: zmax > tau_t always
            if (tnew == tau) break;                     // exact fixed point, uniform
            tau = tnew;
        }
    } else {
        // ---- fallback (degenerate rows, e.g. all-masked): full-scan loop --
        for (int it = 0; it < 50; ++it) {
            float ssum = 0.0f, cnt = 0.0f;
            #pragma unroll
            for (int t = 0; t < V4T; ++t) {
                const fx4 zv = zz[t];
                if (zv.x > tau) { ssum += zv.x; cnt += 1.0f; }
                if (zv.y > tau) { ssum += zv.y; cnt += 1.0f; }
                if (zv.z > tau) { ssum += zv.z; cnt += 1.0f; }
                if (zv.w > tau) { ssum += zv.w; cnt += 1.0f; }
            }
            #pragma unroll
            for (int off = 32; off >= 1; off >>= 1) {
                ssum += __shfl_xor(ssum, off, 64);
                cnt  += __shfl_xor(cnt,  off, 64);
            }
            const int p = it & 1;
            if (lane == 0) { red_sum[p][wid] = ssum; red_cnt[p][wid] = cnt; }
            __syncthreads();
            const float S = ((red_sum[p][0] + red_sum[p][1]) + (red_sum[p][2] + red_sum[p][3]));
            const float C = ((red_cnt[p][0] + red_cnt[p][1]) + (red_cnt[p][2] + red_cnt[p][3]));
            const float tnew = (S - 1.0f) / C;
            if (tnew == tau) break;
            tau = tnew;
        }
    }

    // ---- epilogue: out = min(k * max(z - tau, 0), 1), nontemporal ---------
    #pragma unroll
    for (int t = 0; t < V4T; ++t) {
        const fx4 zv = zz[t];
        fx4 ov;
        ov.x = fminf(kf * fmaxf(zv.x - tau, 0.0f), 1.0f);
        ov.y = fminf(kf * fmaxf(zv.y - tau, 0.0f), 1.0f);
        ov.z = fminf(kf * fmaxf(zv.z - tau, 0.0f), 1.0f);
        ov.w = fminf(kf * fmaxf(zv.w - tau, 0.0f), 1.0f);
        __builtin_nontemporal_store(ov, &ov4[t * BLOCK + tid]);
    }
}

extern "C" void kernel_launch(void* const* d_in, const int* in_sizes, int n_in,
                              void* d_out, int out_size, void* d_ws, size_t ws_size,
                              hipStream_t stream) {
    const float* s = (const float*)d_in[0];
    const float* m = (const float*)d_in[1];
    const int*   k = (const int*)d_in[2];
    float* out = (float*)d_out;

    const int nrows = in_sizes[0] / R_DIM;   // 8192 rows -> 8192 blocks
    gate_sparsemax_k_kernel<<<nrows, BLOCK, 0, stream>>>(s, m, k, out);
}

// Round 3
// 291.973 us; speedup vs baseline: 1.0670x; 1.0105x over previous
//
#include <hip/hip_runtime.h>

// GateSparsemaxK: per-row (R=4096) gated sparsemax, scaled by k, clipped to [0,1].
// z = where(mask>0.5, s, -1e9)/0.7 ; p = sparsemax(z) ; out = min(k*p, 1)
//
// R7 theory: R6 (candidate compaction) was NEUTRAL vs R0 -> the Michelot
// iterate phase is already hidden by TLP (resident blocks overlap each
// other's memory phases). Kernel sits at ~70-74us vs the 402MB/6.29TB/s =
// 64us mixed-stream floor. The remaining ~10% is occupancy: (256,6) leaves
// 6 blocks/CU. This version:
//  1. __launch_bounds__(256,8) -> 32 waves/CU. Fits under the 64-VGPR
//     occupancy boundary by gating IN PLACE (z overwrites the s staging
//     regs; mask regs die after gating) -> peak live ~44 VGPRs.
//  2. Drops R6's candidate/atomic path (proven worthless) - plain full-scan
//     Michelot, LDS back to 3 small arrays.
//  3. Support count via __ballot+__popcll (scalar pipe, wave-uniform):
//     only ssum rides the 6-deep shuffle butterfly.
// If this is neutral, kernel is at the memory roofline (mandatory 402MB).

#define R_DIM 4096
#define BLOCK 256
#define V4T   4                 // float4s per thread: 4096 / 4 / 256
#define BIG_NEG -1.0e9f
#define INV_TAU (1.0f / 0.7f)

typedef float fx4 __attribute__((ext_vector_type(4)));   // builtin-compatible float4

__global__ __launch_bounds__(BLOCK, 8)   // 8 waves/EU -> VGPR<=64, 8 blocks/CU
void gate_sparsemax_k_kernel(const float* __restrict__ s,
                             const float* __restrict__ m,
                             const int*  __restrict__ kptr,
                             float* __restrict__ out)
{
    __shared__ float red_max[4];
    __shared__ float red_sum[2][4];   // ping-pong slots (WAR-safe with 1 barrier)
    __shared__ float red_cnt[2][4];

    const int tid  = (int)threadIdx.x;
    const int lane = tid & 63;
    const int wid  = tid >> 6;
    const int row  = (int)blockIdx.x;

    const float kf = (float)(*kptr);

    const size_t base = (size_t)row * R_DIM;
    const fx4* sv4 = (const fx4*)(s + base);
    const fx4* mv4 = (const fx4*)(m + base);
    fx4*       ov4 = (fx4*)(out + base);

    // ---- issue ALL 8 global loads before any use --------------------------
    fx4 sv[V4T], mv[V4T];
    #pragma unroll
    for (int t = 0; t < V4T; ++t) sv[t] = __builtin_nontemporal_load(&sv4[t * BLOCK + tid]);
    #pragma unroll
    for (int t = 0; t < V4T; ++t) mv[t] = __builtin_nontemporal_load(&mv4[t * BLOCK + tid]);
    __builtin_amdgcn_sched_barrier(0);   // loads stay grouped above their uses

    // ---- gate + scale IN PLACE (z overwrites sv; mv dies here) ------------
    float zmax = -3.4028235e38f;
    #pragma unroll
    for (int t = 0; t < V4T; ++t) {
        fx4 zv;
        zv.x = (mv[t].x > 0.5f ? sv[t].x : BIG_NEG) * INV_TAU;
        zv.y = (mv[t].y > 0.5f ? sv[t].y : BIG_NEG) * INV_TAU;
        zv.z = (mv[t].z > 0.5f ? sv[t].z : BIG_NEG) * INV_TAU;
        zv.w = (mv[t].w > 0.5f ? sv[t].w : BIG_NEG) * INV_TAU;
        sv[t] = zv;
        zmax = fmaxf(zmax, fmaxf(fmaxf(zv.x, zv.y), fmaxf(zv.z, zv.w)));
    }

    // ---- block-wide max: wave butterfly -> 4 LDS words -> combine ---------
    #pragma unroll
    for (int off = 32; off >= 1; off >>= 1)
        zmax = fmaxf(zmax, __shfl_xor(zmax, off, 64));
    if (lane == 0) red_max[wid] = zmax;
    __syncthreads();
    zmax = fmaxf(fmaxf(red_max[0], red_max[1]), fmaxf(red_max[2], red_max[3]));

    // ---- Michelot iterations (exact sparsemax threshold, no sort) ---------
    // tau0 = max-1 <= tau*; tau <- (sum_{z>tau} z - 1)/#{z>tau}. Monotone,
    // support shrinks, terminates exactly at the fixed point. All threads
    // compute identical S,C,tnew -> block-uniform break, barrier-safe.
    float tau = zmax - 1.0f;
    for (int it = 0; it < 50; ++it) {
        float ssum = 0.0f;
        int   cnt  = 0;       // wave-total via ballot popcount (scalar pipe)
        #pragma unroll
        for (int t = 0; t < V4T; ++t) {
            const fx4 zv = sv[t];
            ssum += (zv.x > tau) ? zv.x : 0.0f;
            cnt  += (int)__popcll(__ballot(zv.x > tau));
            ssum += (zv.y > tau) ? zv.y : 0.0f;
            cnt  += (int)__popcll(__ballot(zv.y > tau));
            ssum += (zv.z > tau) ? zv.z : 0.0f;
            cnt  += (int)__popcll(__ballot(zv.z > tau));
            ssum += (zv.w > tau) ? zv.w : 0.0f;
            cnt  += (int)__popcll(__ballot(zv.w > tau));
        }
        #pragma unroll
        for (int off = 32; off >= 1; off >>= 1)
            ssum += __shfl_xor(ssum, off, 64);    // cnt already wave-uniform

        const int p = it & 1;
        if (lane == 0) { red_sum[p][wid] = ssum; red_cnt[p][wid] = (float)cnt; }
        __syncthreads();   // single barrier: ping-pong slot avoids WAR on prev iter
        const float S = ((red_sum[p][0] + red_sum[p][1]) + (red_sum[p][2] + red_sum[p][3]));
        const float C = ((red_cnt[p][0] + red_cnt[p][1]) + (red_cnt[p][2] + red_cnt[p][3]));
        const float tnew = (S - 1.0f) / C;   // C >= 1: the max is always in support
        if (tnew == tau) break;              // exact fixed point, block-uniform
        tau = tnew;
    }

    // ---- epilogue: out = min(k * max(z - tau, 0), 1), nontemporal ---------
    #pragma unroll
    for (int t = 0; t < V4T; ++t) {
        const fx4 zv = sv[t];
        fx4 ov;
        ov.x = fminf(kf * fmaxf(zv.x - tau, 0.0f), 1.0f);
        ov.y = fminf(kf * fmaxf(zv.y - tau, 0.0f), 1.0f);
        ov.z = fminf(kf * fmaxf(zv.z - tau, 0.0f), 1.0f);
        ov.w = fminf(kf * fmaxf(zv.w - tau, 0.0f), 1.0f);
        __builtin_nontemporal_store(ov, &ov4[t * BLOCK + tid]);
    }
}

extern "C" void kernel_launch(void* const* d_in, const int* in_sizes, int n_in,
                              void* d_out, int out_size, void* d_ws, size_t ws_size,
                              hipStream_t stream) {
    const float* s = (const float*)d_in[0];
    const float* m = (const float*)d_in[1];
    const int*   k = (const int*)d_in[2];
    float* out = (float*)d_out;

    const int nrows = in_sizes[0] / R_DIM;   // 8192 rows -> 8192 blocks
    gate_sparsemax_k_kernel<<<nrows, BLOCK, 0, stream>>>(s, m, k, out);
}

// Round 4
// 282.647 us; speedup vs baseline: 1.1022x; 1.0330x over previous
//
#include <hip/hip_runtime.h>

// GateSparsemaxK: per-row (R=4096) gated sparsemax, scaled by k, clipped to [0,1].
// z = where(mask>0.5, s, -1e9)/0.7 ; p = sparsemax(z) ; out = min(k*p, 1)
//
// R8 theory: R7 proved the kernel is TLP-saturated at ~71us for 402.7MB of
// MIXED read+write traffic (5.7 TB/s eff, 90% of the 6.29 TB/s copy ceiling).
// Remaining lever is the STREAM MIX, not the kernel: the output is
// algorithmically sparse (sparsemax support ~1-6 / 4096 per row; >99.8% of
// the 134MB output is exactly 0.0f). Segregate:
//   1. hipMemsetAsync(out) in kernel_launch: pure write stream, runs at the
//      fill rate (6.86 TB/s measured every round) ~= 19.6us.
//   2. Kernel writes ONLY support elements (z > tau): ~200KB scattered
//      scalars. Kernel stream becomes pure-read 268MB ~= 40us.
// Zeros are bit-identical (+0.0 memset == computed +0.0); nonzeros computed
// exactly as R7 -> absmax unchanged. Degenerate all-masked rows (support =
// 4096) still correct, just slow - probability ~0 in this data.
// Predicted: kernel WRITE_SIZE 145MB -> <1MB, dur 71 -> ~40-46us; bench ~283.

#define R_DIM 4096
#define BLOCK 256
#define V4T   4                 // float4s per thread: 4096 / 4 / 256
#define BIG_NEG -1.0e9f
#define INV_TAU (1.0f / 0.7f)

typedef float fx4 __attribute__((ext_vector_type(4)));   // builtin-compatible float4

__global__ __launch_bounds__(BLOCK, 8)   // 8 waves/EU -> VGPR<=64, 8 blocks/CU
void gate_sparsemax_k_kernel(const float* __restrict__ s,
                             const float* __restrict__ m,
                             const int*  __restrict__ kptr,
                             float* __restrict__ out)
{
    __shared__ float red_max[4];
    __shared__ float red_sum[2][4];   // ping-pong slots (WAR-safe with 1 barrier)
    __shared__ float red_cnt[2][4];

    const int tid  = (int)threadIdx.x;
    const int lane = tid & 63;
    const int wid  = tid >> 6;
    const int row  = (int)blockIdx.x;

    const float kf = (float)(*kptr);

    const size_t base = (size_t)row * R_DIM;
    const fx4* sv4 = (const fx4*)(s + base);
    const fx4* mv4 = (const fx4*)(m + base);
    float*     orow = out + base;

    // ---- issue ALL 8 global loads before any use --------------------------
    fx4 sv[V4T], mv[V4T];
    #pragma unroll
    for (int t = 0; t < V4T; ++t) sv[t] = __builtin_nontemporal_load(&sv4[t * BLOCK + tid]);
    #pragma unroll
    for (int t = 0; t < V4T; ++t) mv[t] = __builtin_nontemporal_load(&mv4[t * BLOCK + tid]);
    __builtin_amdgcn_sched_barrier(0);   // loads stay grouped above their uses

    // ---- gate + scale IN PLACE (z overwrites sv; mv dies here) ------------
    float zmax = -3.4028235e38f;
    #pragma unroll
    for (int t = 0; t < V4T; ++t) {
        fx4 zv;
        zv.x = (mv[t].x > 0.5f ? sv[t].x : BIG_NEG) * INV_TAU;
        zv.y = (mv[t].y > 0.5f ? sv[t].y : BIG_NEG) * INV_TAU;
        zv.z = (mv[t].z > 0.5f ? sv[t].z : BIG_NEG) * INV_TAU;
        zv.w = (mv[t].w > 0.5f ? sv[t].w : BIG_NEG) * INV_TAU;
        sv[t] = zv;
        zmax = fmaxf(zmax, fmaxf(fmaxf(zv.x, zv.y), fmaxf(zv.z, zv.w)));
    }

    // ---- block-wide max: wave butterfly -> 4 LDS words -> combine ---------
    #pragma unroll
    for (int off = 32; off >= 1; off >>= 1)
        zmax = fmaxf(zmax, __shfl_xor(zmax, off, 64));
    if (lane == 0) red_max[wid] = zmax;
    __syncthreads();
    zmax = fmaxf(fmaxf(red_max[0], red_max[1]), fmaxf(red_max[2], red_max[3]));

    // ---- Michelot iterations (exact sparsemax threshold, no sort) ---------
    // tau0 = max-1 <= tau*; tau <- (sum_{z>tau} z - 1)/#{z>tau}. Monotone,
    // support shrinks, terminates exactly at the fixed point. All threads
    // compute identical S,C,tnew -> block-uniform break, barrier-safe.
    float tau = zmax - 1.0f;
    for (int it = 0; it < 50; ++it) {
        float ssum = 0.0f;
        int   cnt  = 0;       // wave-total via ballot popcount (scalar pipe)
        #pragma unroll
        for (int t = 0; t < V4T; ++t) {
            const fx4 zv = sv[t];
            ssum += (zv.x > tau) ? zv.x : 0.0f;
            cnt  += (int)__popcll(__ballot(zv.x > tau));
            ssum += (zv.y > tau) ? zv.y : 0.0f;
            cnt  += (int)__popcll(__ballot(zv.y > tau));
            ssum += (zv.z > tau) ? zv.z : 0.0f;
            cnt  += (int)__popcll(__ballot(zv.z > tau));
            ssum += (zv.w > tau) ? zv.w : 0.0f;
            cnt  += (int)__popcll(__ballot(zv.w > tau));
        }
        #pragma unroll
        for (int off = 32; off >= 1; off >>= 1)
            ssum += __shfl_xor(ssum, off, 64);    // cnt already wave-uniform

        const int p = it & 1;
        if (lane == 0) { red_sum[p][wid] = ssum; red_cnt[p][wid] = (float)cnt; }
        __syncthreads();   // single barrier: ping-pong slot avoids WAR on prev iter
        const float S = ((red_sum[p][0] + red_sum[p][1]) + (red_sum[p][2] + red_sum[p][3]));
        const float C = ((red_cnt[p][0] + red_cnt[p][1]) + (red_cnt[p][2] + red_cnt[p][3]));
        const float tnew = (S - 1.0f) / C;   // C >= 1: the max is always in support
        if (tnew == tau) break;              // exact fixed point, block-uniform
        tau = tnew;
    }

    // ---- epilogue: SPARSE write. out was pre-zeroed by hipMemsetAsync; ----
    // only support elements (z > tau) are nonzero: ~1-6 per row. Same
    // arithmetic as the dense store (fmaxf(z-tau,0) == z-tau when z>tau).
    #pragma unroll
    for (int t = 0; t < V4T; ++t) {
        const fx4 zv = sv[t];
        const int i4 = (t * BLOCK + tid) * 4;
        if (zv.x > tau) orow[i4 + 0] = fminf(kf * (zv.x - tau), 1.0f);
        if (zv.y > tau) orow[i4 + 1] = fminf(kf * (zv.y - tau), 1.0f);
        if (zv.z > tau) orow[i4 + 2] = fminf(kf * (zv.z - tau), 1.0f);
        if (zv.w > tau) orow[i4 + 3] = fminf(kf * (zv.w - tau), 1.0f);
    }
}

extern "C" void kernel_launch(void* const* d_in, const int* in_sizes, int n_in,
                              void* d_out, int out_size, void* d_ws, size_t ws_size,
                              hipStream_t stream) {
    const float* s = (const float*)d_in[0];
    const float* m = (const float*)d_in[1];
    const int*   k = (const int*)d_in[2];
    float* out = (float*)d_out;

    // Pure-write stream at fill rate (6.86 TB/s measured): zero the output,
    // kernel then writes only the sparse support. Stream-ordered, capture-safe.
    hipMemsetAsync(out, 0, (size_t)out_size, stream);

    const int nrows = in_sizes[0] / R_DIM;   // 8192 rows -> 8192 blocks
    gate_sparsemax_k_kernel<<<nrows, BLOCK, 0, stream>>>(s, m, k, out);
}